// Round 1
// baseline (173.025 us; speedup 1.0000x reference)
//
#include <hip/hip_runtime.h>
#include <math.h>

#define HIDDEN 64
#define TOTAL  4417   // 5*64 + 1 + 64*64
#define TSTEPS 64

// coefficient layout per batch row:
//   w_ih  [0,   64)
//   w_hh  [64,  4160)   row-major [k][j]: 64 + k*64 + j
//   b_ih  [4160,4224)
//   b_hh  [4224,4288)
//   fc_w  [4288,4352)
//   fc_b  [4352,4353)
//   h0    [4353,4417)

__global__ __launch_bounds__(64, 4)
void rnn_fused_kernel(const float* __restrict__ coeff,
                      const float* __restrict__ xin,
                      float* __restrict__ out)
{
    const int b    = blockIdx.x;
    const int lane = threadIdx.x;              // 0..63, one wave per block

    const float* __restrict__ c = coeff + (size_t)b * TOTAL;

    __shared__ __align__(16) float hsh[HIDDEN];   // h vector, single wave owns it

    // ---- per-lane parameters (coalesced dword loads) ----
    const float wih  = c[lane];
    const float bias = c[4160 + lane] + c[4224 + lane];
    const float fcw  = c[4288 + lane];
    const float fcb  = c[4352];                 // uniform broadcast load
    const float h0   = c[4353 + lane];
    const float xv   = xin[(size_t)b * TSTEPS + lane];  // lane t holds x[b][t]

    // ---- W row into registers: lane k owns w_hh[b][k][*] (64 VGPRs) ----
    float W[HIDDEN];
    const float* __restrict__ wrow = c + 64 + lane * HIDDEN;
    #pragma unroll
    for (int j = 0; j < HIDDEN; ++j) W[j] = wrow[j];

    hsh[lane] = h0;
    __syncthreads();

    float hn = h0;

    #pragma unroll 1
    for (int t = 0; t < TSTEPS; ++t) {
        const float xt  = __shfl(xv, t, 64);     // uniform broadcast of x[b][t]
        float acc = fmaf(xt, wih, bias);

        // acc += sum_j h[j] * W[lane][j], h broadcast from LDS
        #pragma unroll
        for (int j4 = 0; j4 < HIDDEN / 4; ++j4) {
            const float4 hv = *reinterpret_cast<const float4*>(&hsh[j4 * 4]);
            acc = fmaf(hv.x, W[4 * j4 + 0], acc);
            acc = fmaf(hv.y, W[4 * j4 + 1], acc);
            acc = fmaf(hv.z, W[4 * j4 + 2], acc);
            acc = fmaf(hv.w, W[4 * j4 + 3], acc);
        }

        // tanh(a) = 1 - 2/(e^{2a}+1); robust at +-inf
        const float e = __expf(acc + acc);
        hn = 1.0f - 2.0f * __builtin_amdgcn_rcpf(e + 1.0f);

        __syncthreads();          // all reads of old h done (wave-local, cheap)
        hsh[lane] = hn;
        __syncthreads();          // new h visible to all lanes
    }

    // ---- readout: pred = sum_k h[k]*fc_w[k] + fc_b ----
    float p = hn * fcw;
    #pragma unroll
    for (int off = 32; off > 0; off >>= 1)
        p += __shfl_xor(p, off, 64);

    if (lane == 0) out[b] = p + fcb;
}

extern "C" void kernel_launch(void* const* d_in, const int* in_sizes, int n_in,
                              void* d_out, int out_size, void* d_ws, size_t ws_size,
                              hipStream_t stream)
{
    const float* coeff = (const float*)d_in[0];
    const float* xin   = (const float*)d_in[1];
    float* out         = (float*)d_out;

    const int B = in_sizes[0] / TOTAL;   // 16384

    rnn_fused_kernel<<<B, HIDDEN, 0, stream>>>(coeff, xin, out);
}

// Round 2
// 158.752 us; speedup vs baseline: 1.0899x; 1.0899x over previous
//
#include <hip/hip_runtime.h>
#include <math.h>

#define HIDDEN 64
#define TOTAL  4417   // 5*64 + 1 + 64*64
#define TSTEPS 64

// coefficient layout per batch row:
//   w_ih  [0,   64)
//   w_hh  [64,  4160)   row-major [k][j]: 64 + k*64 + j
//   b_ih  [4160,4224)
//   b_hh  [4224,4288)
//   fc_w  [4288,4352)
//   fc_b  [4352,4353)
//   h0    [4353,4417)

__global__ __launch_bounds__(64, 4)
void rnn_fused_kernel(const float* __restrict__ coeff,
                      const float* __restrict__ xin,
                      float* __restrict__ out)
{
    const int b    = blockIdx.x;
    const int lane = threadIdx.x;              // 0..63, one wave per block

    const float* __restrict__ c = coeff + (size_t)b * TOTAL;

    __shared__ __align__(16) float hsh[HIDDEN];   // h vector (single-wave block)

    // ---- per-lane parameters ----
    const float wih  = c[lane];
    const float bias = c[4160 + lane] + c[4224 + lane];
    const float fcw  = c[4288 + lane];
    const float fcb  = c[4352];
    const float h0   = c[4353 + lane];
    const float xv   = xin[(size_t)b * TSTEPS + lane];  // lane t holds x[b][t]

    // ---- W row into registers: lane k owns w_hh[b][k][*] ----
    float W[HIDDEN];
    const float* __restrict__ wrow = c + HIDDEN + lane * HIDDEN;
    #pragma unroll
    for (int j = 0; j < HIDDEN; ++j) W[j] = wrow[j];
    // Pin W in VGPRs. R1 showed VGPR_Count=44: the compiler sank these loads
    // into the time loop and re-fetched W every step. The asm keep-alive makes
    // each W[j] an unrematerializable register value before the loop.
    #pragma unroll
    for (int j = 0; j < HIDDEN; ++j) asm volatile("" : "+v"(W[j]));

    hsh[lane] = h0;
    __builtin_amdgcn_wave_barrier();   // DS ops of one wave execute in order;
                                       // only compile-time ordering needed.

    float hn = h0;

    #pragma unroll 1
    for (int t = 0; t < TSTEPS; ++t) {
        // uniform broadcast of x[b][t] via readlane (t is an SGPR loop index)
        const float xt = __int_as_float(
            __builtin_amdgcn_readlane(__float_as_int(xv), t));
        float acc = fmaf(xt, wih, bias);

        // acc += sum_j h[j] * W[lane][j]; h broadcast-read from LDS (conflict-free)
        #pragma unroll
        for (int j4 = 0; j4 < HIDDEN / 4; ++j4) {
            const float4 hv = *reinterpret_cast<const float4*>(&hsh[j4 * 4]);
            acc = fmaf(hv.x, W[4 * j4 + 0], acc);
            acc = fmaf(hv.y, W[4 * j4 + 1], acc);
            acc = fmaf(hv.z, W[4 * j4 + 2], acc);
            acc = fmaf(hv.w, W[4 * j4 + 3], acc);
        }

        // tanh(a) = 1 - 2/(e^{2a}+1); robust at +-inf
        const float e = __expf(acc + acc);
        hn = 1.0f - 2.0f * __builtin_amdgcn_rcpf(e + 1.0f);

        __builtin_amdgcn_wave_barrier();  // all reads of old h precede the write
        hsh[lane] = hn;
        __builtin_amdgcn_wave_barrier();  // write precedes next-iter reads
    }

    // ---- readout: pred = sum_k h[k]*fc_w[k] + fc_b ----
    float p = hn * fcw;
    #pragma unroll
    for (int off = 32; off > 0; off >>= 1)
        p += __shfl_xor(p, off, 64);

    if (lane == 0) out[b] = p + fcb;
}

extern "C" void kernel_launch(void* const* d_in, const int* in_sizes, int n_in,
                              void* d_out, int out_size, void* d_ws, size_t ws_size,
                              hipStream_t stream)
{
    const float* coeff = (const float*)d_in[0];
    const float* xin   = (const float*)d_in[1];
    float* out         = (float*)d_out;

    const int B = in_sizes[0] / TOTAL;   // 16384

    rnn_fused_kernel<<<B, HIDDEN, 0, stream>>>(coeff, xin, out);
}